// Round 5
// baseline (371.546 us; speedup 1.0000x reference)
//
#include <hip/hip_runtime.h>
#include <hip/hip_bf16.h>

#define NF     128
#define BATCH  64
#define NNODES 4096
#define MROWS  (BATCH * NNODES)       // 262144
#define NEDGE  (BATCH * (NNODES - 1)) // 262080
#define LN_EPS 1e-5f
#define AP     136                    // padded stride (shorts) for out-repack

typedef short  short8  __attribute__((ext_vector_type(8)));
typedef float  float4v __attribute__((ext_vector_type(4)));

__device__ __forceinline__ unsigned short f2bf(float f) {
    union { float f; unsigned u; } v; v.f = f;
    unsigned r = v.u;
    r = r + 0x7FFF + ((r >> 16) & 1);   // RNE
    return (unsigned short)(r >> 16);
}
__device__ __forceinline__ float bf2f(unsigned short b) {
    union { unsigned u; float f; } v; v.u = ((unsigned)b) << 16;
    return v.f;
}
// packed f32x2 -> bf16x2 (v_cvt_pk_bf16_f32 on gfx950), low short = lo
__device__ __forceinline__ unsigned pkbf(float lo, float hi) {
    __hip_bfloat162 h = __float22bfloat162_rn(float2{lo, hi});
    union { __hip_bfloat162 h; unsigned u; } v; v.h = h;
    return v.u;
}

// A-fragment slot address (shorts) in a wave's buffer. slot(q,m) holds
// A[m][q*8..q*8+7]; XOR swizzle keeps edge-writer conflict-free. (validated r4)
__device__ __forceinline__ int slotAddr(int q, int m) {
    return ((q * 16 + m) ^ (q & 7)) * 8;
}

// Stage W (128x128 fp32, k-major) into WF as bf16 MFMA B-fragment order:
// fragment id fid = c*4+s; element (k,n): lane = ((k&31)>>3)*16 + (n&15),
// j = k&7.  Layout: WF[(fid*64+lane)*8 + j]. 1024 threads, coalesced reads.
__device__ __forceinline__ void stage_wfrags(const float* __restrict__ W,
                                             unsigned short* __restrict__ WF,
                                             int tid) {
    #pragma unroll
    for (int i = 0; i < 4; ++i) {
        int g  = tid + 1024 * i;          // 0..4095
        int k  = g >> 5;                  // 0..127
        int n0 = (g & 31) * 4;
        float4v wv = *(const float4v*)(W + k * NF + n0);
        int s = k >> 5, q = (k & 31) >> 3, j = k & 7;
        #pragma unroll
        for (int e = 0; e < 4; ++e) {
            int n = n0 + e;
            WF[((((n >> 4) * 4 + s) * 64) + q * 16 + (n & 15)) * 8 + j] = f2bf(wv[e]);
        }
    }
}

// bias + LayerNorm(128) + ELU on C-layout accumulators.
// PI: interleaved params PI[n*4 + {0:bias,1:gain,2:beta}].
__device__ __forceinline__ void ln_elu(float4v acc[8], const float* __restrict__ PI,
                                       int lnm) {
    float bias[8], gn[8], bt[8];
    #pragma unroll
    for (int c = 0; c < 8; ++c) {
        float4v prm = *(const float4v*)&PI[(c * 16 + lnm) * 4];
        bias[c] = prm[0]; gn[c] = prm[1]; bt[c] = prm[2];
    }
    #pragma unroll
    for (int r = 0; r < 4; ++r) {
        float s1 = 0.f, s2 = 0.f;
        #pragma unroll
        for (int c = 0; c < 8; ++c) {
            float t = acc[c][r] + bias[c];
            acc[c][r] = t;
            s1 += t; s2 += t * t;
        }
        #pragma unroll
        for (int m = 1; m < 16; m <<= 1) {
            s1 += __shfl_xor(s1, m, 16);
            s2 += __shfl_xor(s2, m, 16);
        }
        float mu  = s1 * (1.0f / 128.0f);
        float var = s2 * (1.0f / 128.0f) - mu * mu;
        float rs  = rsqrtf(var + LN_EPS);
        #pragma unroll
        for (int c = 0; c < 8; ++c) {
            float y = (acc[c][r] - mu) * rs * gn[c] + bt[c];
            acc[c][r] = (y > 0.f) ? y : (__expf(y) - 1.0f);
        }
    }
}

// ---------------- fused layer1+layer2 ----------------
// LDS carve (shorts):  WF1 [0,16384) | WF2 [16384,32768) |
//   MYF [32768, 32768+16*2176) | PI (floats) at 67584 shorts: 2 sets x 512 f
#define F_MYF   32768
#define F_PI    67584
#define F_TOT   (67584 + 1024 * 2)      // shorts: 139264 B total

__global__ __launch_bounds__(1024)
void fused12_kernel(const float* __restrict__ x,
                    const float* __restrict__ W1, const float* __restrict__ b1,
                    const float* __restrict__ g1, const float* __restrict__ be1,
                    const float* __restrict__ W2, const float* __restrict__ b2,
                    const float* __restrict__ g2, const float* __restrict__ be2,
                    unsigned short* __restrict__ h2out)
{
    __shared__ __align__(16) unsigned short SH[F_TOT];

    const int tid  = threadIdx.x;
    const int lane = tid & 63;
    const int wave = tid >> 6;        // 0..15
    const int lnm  = lane & 15;
    const int qu   = lane >> 4;

    stage_wfrags(W1, &SH[0], tid);
    stage_wfrags(W2, &SH[16384], tid);
    float* PIf = (float*)&SH[F_PI];
    if (tid < NF) {
        PIf[tid * 4 + 0] = b1[tid]; PIf[tid * 4 + 1] = g1[tid]; PIf[tid * 4 + 2] = be1[tid];
        PIf[512 + tid * 4 + 0] = b2[tid]; PIf[512 + tid * 4 + 1] = g2[tid];
        PIf[512 + tid * 4 + 2] = be2[tid];
    }

    unsigned short* myF = &SH[F_MYF + wave * 2176];
    const unsigned short* WF1 = &SH[0];
    const unsigned short* WF2 = &SH[16384];

    const int nstrips = MROWS / 16;          // 16384
    const int sstep   = gridDim.x * 16;      // 4096
    int strip = blockIdx.x * 16 + wave;

    float4v rx[8];
    if (strip < nstrips) {
        const float* xs = x + (size_t)strip * (16 * NF);
        #pragma unroll
        for (int t = 0; t < 8; ++t)
            rx[t] = *(const float4v*)(xs + t * 256 + lane * 4);
    }
    __syncthreads();

    const int qx = (lane & 31) >> 1;   // k-octet of this lane's x chunk
    const int hx = (lane & 1) * 4;     // half-slot offset (shorts)

    for (; strip < nstrips; strip += sstep) {
        // rx -> A slots (lane holds rows t*2+(lane>>5), cols (lane&31)*4..+3)
        #pragma unroll
        for (int t = 0; t < 8; ++t) {
            int m = t * 2 + (lane >> 5);
            uint2 u = { pkbf(rx[t][0], rx[t][1]), pkbf(rx[t][2], rx[t][3]) };
            *(uint2*)&myF[slotAddr(qx, m) + hx] = u;
        }
        // prefetch strip i+1 (in flight through all compute below)
        int sn = strip + sstep;
        if (sn < nstrips) {
            const float* xs = x + (size_t)sn * (16 * NF);
            #pragma unroll
            for (int t = 0; t < 8; ++t)
                rx[t] = *(const float4v*)(xs + t * 256 + lane * 4);
        }

        // layer 1 (B-fragments streamed from LDS)
        float4v acc[8];
        #pragma unroll
        for (int c = 0; c < 8; ++c) acc[c] = (float4v){0.f, 0.f, 0.f, 0.f};
        #pragma unroll
        for (int s = 0; s < 4; ++s) {
            short8 af = *(const short8*)&myF[slotAddr(s * 4 + qu, lnm)];
            #pragma unroll
            for (int c = 0; c < 8; ++c) {
                short8 bfv = *(const short8*)&WF1[((c * 4 + s) * 64 + lane) * 8];
                acc[c] = __builtin_amdgcn_mfma_f32_16x16x32_bf16(af, bfv, acc[c], 0, 0, 0);
            }
        }
        ln_elu(acc, PIf, lnm);

        // repack h1 (C layout) -> A slots for layer 2 (in-wave)
        #pragma unroll
        for (int c = 0; c < 8; ++c) {
            int qq = c * 2 + (lnm >> 3), j = lnm & 7;
            #pragma unroll
            for (int r = 0; r < 4; ++r)
                myF[slotAddr(qq, qu * 4 + r) + j] = f2bf(acc[c][r]);
        }

        // layer 2
        #pragma unroll
        for (int c = 0; c < 8; ++c) acc[c] = (float4v){0.f, 0.f, 0.f, 0.f};
        #pragma unroll
        for (int s = 0; s < 4; ++s) {
            short8 af = *(const short8*)&myF[slotAddr(s * 4 + qu, lnm)];
            #pragma unroll
            for (int c = 0; c < 8; ++c) {
                short8 bfv = *(const short8*)&WF2[((c * 4 + s) * 64 + lane) * 8];
                acc[c] = __builtin_amdgcn_mfma_f32_16x16x32_bf16(af, bfv, acc[c], 0, 0, 0);
            }
        }
        ln_elu(acc, PIf + 512, lnm);

        // out-repack (row-major, padded) + coalesced 1-KiB stores
        #pragma unroll
        for (int c = 0; c < 8; ++c)
            #pragma unroll
            for (int r = 0; r < 4; ++r)
                myF[(qu * 4 + r) * AP + c * 16 + lnm] = f2bf(acc[c][r]);

        unsigned short* ob = h2out + (size_t)strip * (16 * NF);
        #pragma unroll
        for (int t = 0; t < 4; ++t) {
            int row = t * 4 + (lane >> 4);
            short8 pk = *(const short8*)&myF[row * AP + (lane & 15) * 8];
            *(short8*)(ob + t * 512 + lane * 8) = pk;
        }
    }
}

// ---------------- edge kernel ----------------
// LDS carve: WFr [0,16384) | MYF [16384, 16384+16*2176) | PI at 51200 shorts
#define E_MYF   16384
#define E_PI    51200
#define E_TOT   (51200 + 1024)          // shorts: 104448 B

__global__ __launch_bounds__(1024)
void edge_kernel(const unsigned short* __restrict__ h2,
                 const int* __restrict__ pidx,
                 const float* __restrict__ Wr1, const float* __restrict__ br1,
                 const float* __restrict__ gr1, const float* __restrict__ ber1,
                 const float* __restrict__ Wr2, const float* __restrict__ br2,
                 float* __restrict__ rout)
{
    __shared__ __align__(16) unsigned short SH[E_TOT];

    const int tid  = threadIdx.x;
    const int lane = tid & 63;
    const int wave = tid >> 6;
    const int lnm  = lane & 15;
    const int qu   = lane >> 4;

    stage_wfrags(Wr1, &SH[0], tid);
    float* PIf = (float*)&SH[E_PI];
    if (tid < NF) {
        PIf[tid * 4 + 0] = br1[tid]; PIf[tid * 4 + 1] = gr1[tid];
        PIf[tid * 4 + 2] = ber1[tid];
    }

    float w2c[8];
    #pragma unroll
    for (int c = 0; c < 8; ++c) w2c[c] = Wr2[c * 16 + lnm];
    const float br2v = br2[0];

    unsigned short* myF = &SH[E_MYF + wave * 2176];
    const unsigned short* WFr = &SH[0];

    const int nstrips = NEDGE / 16;          // 16380
    const int sstep   = gridDim.x * 16;      // 4096
    const int s0      = blockIdx.x * 16 + wave;

    short8 cv[4], pv[4];
    int prn[4];
    if (s0 < nstrips) {
        int pr[4];
        #pragma unroll
        for (int t = 0; t < 4; ++t) pr[t] = pidx[s0 * 16 + t * 4 + qu];
        #pragma unroll
        for (int t = 0; t < 4; ++t) {
            int e = s0 * 16 + t * 4 + qu;
            int crow = e + (int)((unsigned)e / 4095u);
            cv[t] = *(const short8*)(h2 + (size_t)crow * NF + lnm * 8);
            pv[t] = *(const short8*)(h2 + (size_t)pr[t] * NF + lnm * 8);
        }
        int s1 = s0 + sstep;
        if (s1 < nstrips) {
            #pragma unroll
            for (int t = 0; t < 4; ++t) prn[t] = pidx[s1 * 16 + t * 4 + qu];
        }
    }
    __syncthreads();

    for (int strip = s0; strip < nstrips; strip += sstep) {
        // max + convert -> A slots (edge m = t*4+qu, k = lnm*8..+7)
        #pragma unroll
        for (int t = 0; t < 4; ++t) {
            union { short8 v; unsigned short e8[8]; } u;
            #pragma unroll
            for (int j = 0; j < 8; ++j)
                u.e8[j] = f2bf(fmaxf(bf2f((unsigned short)cv[t][j]),
                                     bf2f((unsigned short)pv[t][j])));
            *(short8*)&myF[slotAddr(lnm, t * 4 + qu)] = u.v;
        }

        // prefetch next strip's rows (pidx already in prn), pidx two ahead
        int sn = strip + sstep;
        if (sn < nstrips) {
            #pragma unroll
            for (int t = 0; t < 4; ++t) {
                int e = sn * 16 + t * 4 + qu;
                int crow = e + (int)((unsigned)e / 4095u);
                cv[t] = *(const short8*)(h2 + (size_t)crow * NF + lnm * 8);
                pv[t] = *(const short8*)(h2 + (size_t)prn[t] * NF + lnm * 8);
            }
            int sn2 = sn + sstep;
            if (sn2 < nstrips) {
                #pragma unroll
                for (int t = 0; t < 4; ++t) prn[t] = pidx[sn2 * 16 + t * 4 + qu];
            }
        }

        // MFMA + LN/ELU + dot(Wr2)
        float4v acc[8];
        #pragma unroll
        for (int c = 0; c < 8; ++c) acc[c] = (float4v){0.f, 0.f, 0.f, 0.f};
        #pragma unroll
        for (int s = 0; s < 4; ++s) {
            short8 af = *(const short8*)&myF[slotAddr(s * 4 + qu, lnm)];
            #pragma unroll
            for (int c = 0; c < 8; ++c) {
                short8 bfv = *(const short8*)&WFr[((c * 4 + s) * 64 + lane) * 8];
                acc[c] = __builtin_amdgcn_mfma_f32_16x16x32_bf16(af, bfv, acc[c], 0, 0, 0);
            }
        }
        ln_elu(acc, PIf, lnm);

        #pragma unroll
        for (int r = 0; r < 4; ++r) {
            float t2 = 0.f;
            #pragma unroll
            for (int c = 0; c < 8; ++c) t2 += acc[c][r] * w2c[c];
            #pragma unroll
            for (int m = 1; m < 16; m <<= 1) t2 += __shfl_xor(t2, m, 16);
            if (lnm == 0) rout[strip * 16 + qu * 4 + r] = t2 + br2v;
        }
    }
}

__global__ __launch_bounds__(256)
void lse_kernel(const float* __restrict__ r, float* __restrict__ out)
{
    __shared__ float red[256];
    const int b = blockIdx.x;
    const float* rb = r + (size_t)b * 4095;

    float mx = -1e30f;
    for (int i = threadIdx.x; i < 4095; i += 256) mx = fmaxf(mx, rb[i]);
    red[threadIdx.x] = mx;
    __syncthreads();
    for (int s = 128; s > 0; s >>= 1) {
        if (threadIdx.x < s) red[threadIdx.x] = fmaxf(red[threadIdx.x], red[threadIdx.x + s]);
        __syncthreads();
    }
    mx = red[0];
    __syncthreads();

    float sum = 0.f;
    for (int i = threadIdx.x; i < 4095; i += 256) sum += __expf(rb[i] - mx);
    red[threadIdx.x] = sum;
    __syncthreads();
    for (int s = 128; s > 0; s >>= 1) {
        if (threadIdx.x < s) red[threadIdx.x] += red[threadIdx.x + s];
        __syncthreads();
    }
    float lse = mx + __logf(red[0]);

    for (int i = threadIdx.x; i < 4095; i += 256)
        out[(size_t)b * 4095 + i] = rb[i] - lse;
}

extern "C" void kernel_launch(void* const* d_in, const int* in_sizes, int n_in,
                              void* d_out, int out_size, void* d_ws, size_t ws_size,
                              hipStream_t stream)
{
    const float* x    = (const float*)d_in[0];
    const int*   pidx = (const int*)d_in[1];
    const float* W1   = (const float*)d_in[2];
    const float* b1   = (const float*)d_in[3];
    const float* g1   = (const float*)d_in[4];
    const float* be1  = (const float*)d_in[5];
    const float* W2   = (const float*)d_in[6];
    const float* b2   = (const float*)d_in[7];
    const float* g2   = (const float*)d_in[8];
    const float* be2  = (const float*)d_in[9];
    const float* Wr1  = (const float*)d_in[10];
    const float* br1  = (const float*)d_in[11];
    const float* gr1  = (const float*)d_in[12];
    const float* ber1 = (const float*)d_in[13];
    const float* Wr2  = (const float*)d_in[14];
    const float* br2  = (const float*)d_in[15];
    float* out = (float*)d_out;

    // workspace: h2 (bf16, 64 MiB) | rbuf (fp32, ~1 MiB)
    unsigned short* h2 = (unsigned short*)d_ws;
    float* rbuf = (float*)(h2 + (size_t)MROWS * NF);

    fused12_kernel<<<256, 1024, 0, stream>>>(x, W1, b1, g1, be1,
                                             W2, b2, g2, be2, h2);
    edge_kernel<<<256, 1024, 0, stream>>>(h2, pidx, Wr1, br1, gr1, ber1,
                                          Wr2, br2, rbuf);
    lse_kernel<<<BATCH, 256, 0, stream>>>(rbuf, out);
}

// Round 6
// 354.403 us; speedup vs baseline: 1.0484x; 1.0484x over previous
//
#include <hip/hip_runtime.h>
#include <hip/hip_bf16.h>

#define NF     128
#define BATCH  64
#define NNODES 4096
#define MROWS  (BATCH * NNODES)       // 262144
#define NEDGE  (BATCH * (NNODES - 1)) // 262080
#define LN_EPS 1e-5f
#define AP     136                    // padded stride (shorts) for out-repack

typedef short  short8  __attribute__((ext_vector_type(8)));
typedef float  float4v __attribute__((ext_vector_type(4)));

__device__ __forceinline__ unsigned short f2bf(float f) {
    union { float f; unsigned u; } v; v.f = f;
    unsigned r = v.u;
    r = r + 0x7FFF + ((r >> 16) & 1);   // RNE
    return (unsigned short)(r >> 16);
}
__device__ __forceinline__ float bf2f(unsigned short b) {
    union { unsigned u; float f; } v; v.u = ((unsigned)b) << 16;
    return v.f;
}
// packed f32x2 -> bf16x2 (v_cvt_pk_bf16_f32 on gfx950), low short = lo
__device__ __forceinline__ unsigned pkbf(float lo, float hi) {
    __hip_bfloat162 h = __float22bfloat162_rn(float2{lo, hi});
    union { __hip_bfloat162 h; unsigned u; } v; v.h = h;
    return v.u;
}

// ---- DPP 16-lane sum (VALU pipe, no LDS): quad_perm ^1, ^2, then
// row_half_mirror (== ^4 once quads uniform), row_mirror (== ^8 once halves
// uniform). Exact for sum-reductions over aligned 16-lane groups.
template <int CTRL>
__device__ __forceinline__ float dppadd(float v) {
    union { float f; int i; } a, b; a.f = v;
    b.i = __builtin_amdgcn_mov_dpp(a.i, CTRL, 0xF, 0xF, true);
    return v + b.f;
}
__device__ __forceinline__ float red16(float v) {
    v = dppadd<0xB1>(v);    // quad_perm [1,0,3,2]  (^1)
    v = dppadd<0x4E>(v);    // quad_perm [2,3,0,1]  (^2)
    v = dppadd<0x141>(v);   // row_half_mirror      (^7 == ^4 after uniform-4)
    v = dppadd<0x140>(v);   // row_mirror           (^15 == ^8 after uniform-8)
    return v;
}

// A-fragment slot address (shorts) in a wave's buffer. slot(q,m) holds
// A[m][q*8..q*8+7]; XOR swizzle keeps edge-writer conflict-free. (validated r4)
__device__ __forceinline__ int slotAddr(int q, int m) {
    return ((q * 16 + m) ^ (q & 7)) * 8;
}

// Stage W (128x128 fp32, k-major) into WF as bf16 MFMA B-fragment order:
// fragment id fid = c*4+s; element (k,n): lane = ((k&31)>>3)*16 + (n&15),
// j = k&7.  Layout: WF[(fid*64+lane)*8 + j]. 1024 threads, coalesced reads.
__device__ __forceinline__ void stage_wfrags(const float* __restrict__ W,
                                             unsigned short* __restrict__ WF,
                                             int tid) {
    #pragma unroll
    for (int i = 0; i < 4; ++i) {
        int g  = tid + 1024 * i;          // 0..4095
        int k  = g >> 5;                  // 0..127
        int n0 = (g & 31) * 4;
        float4v wv = *(const float4v*)(W + k * NF + n0);
        int s = k >> 5, q = (k & 31) >> 3, j = k & 7;
        #pragma unroll
        for (int e = 0; e < 4; ++e) {
            int n = n0 + e;
            WF[((((n >> 4) * 4 + s) * 64) + q * 16 + (n & 15)) * 8 + j] = f2bf(wv[e]);
        }
    }
}

// bias + LayerNorm(128) + ELU on C-layout accumulators.
// PI: interleaved params PI[n*4 + {0:bias,1:gain,2:beta}].
__device__ __forceinline__ void ln_elu(float4v acc[8], const float* __restrict__ PI,
                                       int lnm) {
    float bias[8], gn[8], bt[8];
    #pragma unroll
    for (int c = 0; c < 8; ++c) {
        float4v prm = *(const float4v*)&PI[(c * 16 + lnm) * 4];
        bias[c] = prm[0]; gn[c] = prm[1]; bt[c] = prm[2];
    }
    #pragma unroll
    for (int r = 0; r < 4; ++r) {
        float s1 = 0.f, s2 = 0.f;
        #pragma unroll
        for (int c = 0; c < 8; ++c) {
            float t = acc[c][r] + bias[c];
            acc[c][r] = t;
            s1 += t; s2 += t * t;
        }
        s1 = red16(s1);
        s2 = red16(s2);
        float mu  = s1 * (1.0f / 128.0f);
        float var = s2 * (1.0f / 128.0f) - mu * mu;
        float rs  = rsqrtf(var + LN_EPS);
        #pragma unroll
        for (int c = 0; c < 8; ++c) {
            float y = (acc[c][r] - mu) * rs * gn[c] + bt[c];
            acc[c][r] = (y > 0.f) ? y : (__expf(y) - 1.0f);
        }
    }
}

// ---------------- fused layer1+layer2 ----------------
// LDS carve (shorts):  WF1 [0,16384) | WF2 [16384,32768) |
//   MYF [32768, 32768+16*2176) | PI (floats) at 67584 shorts: 2 sets x 512 f
#define F_MYF   32768
#define F_PI    67584
#define F_TOT   (67584 + 1024 * 2)      // shorts: 139264 B total

__global__ __launch_bounds__(1024)
void fused12_kernel(const float* __restrict__ x,
                    const float* __restrict__ W1, const float* __restrict__ b1,
                    const float* __restrict__ g1, const float* __restrict__ be1,
                    const float* __restrict__ W2, const float* __restrict__ b2,
                    const float* __restrict__ g2, const float* __restrict__ be2,
                    unsigned short* __restrict__ h2out)
{
    __shared__ __align__(16) unsigned short SH[F_TOT];

    const int tid  = threadIdx.x;
    const int lane = tid & 63;
    const int wave = tid >> 6;        // 0..15
    const int lnm  = lane & 15;
    const int qu   = lane >> 4;

    stage_wfrags(W1, &SH[0], tid);
    stage_wfrags(W2, &SH[16384], tid);
    float* PIf = (float*)&SH[F_PI];
    if (tid < NF) {
        PIf[tid * 4 + 0] = b1[tid]; PIf[tid * 4 + 1] = g1[tid]; PIf[tid * 4 + 2] = be1[tid];
        PIf[512 + tid * 4 + 0] = b2[tid]; PIf[512 + tid * 4 + 1] = g2[tid];
        PIf[512 + tid * 4 + 2] = be2[tid];
    }

    unsigned short* myF = &SH[F_MYF + wave * 2176];
    const unsigned short* WF1 = &SH[0];
    const unsigned short* WF2 = &SH[16384];

    const int nstrips = MROWS / 16;          // 16384
    const int sstep   = gridDim.x * 16;      // 4096
    int strip = blockIdx.x * 16 + wave;

    float4v rx[8];
    if (strip < nstrips) {
        const float* xs = x + (size_t)strip * (16 * NF);
        #pragma unroll
        for (int t = 0; t < 8; ++t)
            rx[t] = *(const float4v*)(xs + t * 256 + lane * 4);
    }
    __syncthreads();

    const int qx = (lane & 31) >> 1;   // k-octet of this lane's x chunk
    const int hx = (lane & 1) * 4;     // half-slot offset (shorts)

    for (; strip < nstrips; strip += sstep) {
        // rx -> A slots (lane holds rows t*2+(lane>>5), cols (lane&31)*4..+3)
        #pragma unroll
        for (int t = 0; t < 8; ++t) {
            int m = t * 2 + (lane >> 5);
            uint2 u = { pkbf(rx[t][0], rx[t][1]), pkbf(rx[t][2], rx[t][3]) };
            *(uint2*)&myF[slotAddr(qx, m) + hx] = u;
        }
        // prefetch strip i+1 (in flight through all compute below)
        int sn = strip + sstep;
        if (sn < nstrips) {
            const float* xs = x + (size_t)sn * (16 * NF);
            #pragma unroll
            for (int t = 0; t < 8; ++t)
                rx[t] = *(const float4v*)(xs + t * 256 + lane * 4);
        }

        // layer 1 (B-fragments streamed from LDS)
        float4v acc[8];
        #pragma unroll
        for (int c = 0; c < 8; ++c) acc[c] = (float4v){0.f, 0.f, 0.f, 0.f};
        #pragma unroll
        for (int s = 0; s < 4; ++s) {
            short8 af = *(const short8*)&myF[slotAddr(s * 4 + qu, lnm)];
            #pragma unroll
            for (int c = 0; c < 8; ++c) {
                short8 bfv = *(const short8*)&WF1[((c * 4 + s) * 64 + lane) * 8];
                acc[c] = __builtin_amdgcn_mfma_f32_16x16x32_bf16(af, bfv, acc[c], 0, 0, 0);
            }
        }
        ln_elu(acc, PIf, lnm);

        // repack h1 (C layout) -> A slots for layer 2 (in-wave)
        #pragma unroll
        for (int c = 0; c < 8; ++c) {
            int qq = c * 2 + (lnm >> 3), j = lnm & 7;
            #pragma unroll
            for (int r = 0; r < 4; ++r)
                myF[slotAddr(qq, qu * 4 + r) + j] = f2bf(acc[c][r]);
        }

        // layer 2
        #pragma unroll
        for (int c = 0; c < 8; ++c) acc[c] = (float4v){0.f, 0.f, 0.f, 0.f};
        #pragma unroll
        for (int s = 0; s < 4; ++s) {
            short8 af = *(const short8*)&myF[slotAddr(s * 4 + qu, lnm)];
            #pragma unroll
            for (int c = 0; c < 8; ++c) {
                short8 bfv = *(const short8*)&WF2[((c * 4 + s) * 64 + lane) * 8];
                acc[c] = __builtin_amdgcn_mfma_f32_16x16x32_bf16(af, bfv, acc[c], 0, 0, 0);
            }
        }
        ln_elu(acc, PIf + 512, lnm);

        // out-repack (row-major, padded) + coalesced 1-KiB stores
        #pragma unroll
        for (int c = 0; c < 8; ++c)
            #pragma unroll
            for (int r = 0; r < 4; ++r)
                myF[(qu * 4 + r) * AP + c * 16 + lnm] = f2bf(acc[c][r]);

        unsigned short* ob = h2out + (size_t)strip * (16 * NF);
        #pragma unroll
        for (int t = 0; t < 4; ++t) {
            int row = t * 4 + (lane >> 4);
            short8 pk = *(const short8*)&myF[row * AP + (lane & 15) * 8];
            *(short8*)(ob + t * 512 + lane * 8) = pk;
        }
    }
}

// ---------------- edge kernel ----------------
// LDS carve: WFr [0,16384) | MYF [16384, 16384+16*2176) | PI at 51200 shorts
#define E_MYF   16384
#define E_PI    51200
#define E_TOT   (51200 + 1024)          // shorts: 104448 B

__global__ __launch_bounds__(1024)
void edge_kernel(const unsigned short* __restrict__ h2,
                 const int* __restrict__ pidx,
                 const float* __restrict__ Wr1, const float* __restrict__ br1,
                 const float* __restrict__ gr1, const float* __restrict__ ber1,
                 const float* __restrict__ Wr2, const float* __restrict__ br2,
                 float* __restrict__ rout)
{
    __shared__ __align__(16) unsigned short SH[E_TOT];

    const int tid  = threadIdx.x;
    const int lane = tid & 63;
    const int wave = tid >> 6;
    const int lnm  = lane & 15;
    const int qu   = lane >> 4;

    stage_wfrags(Wr1, &SH[0], tid);
    float* PIf = (float*)&SH[E_PI];
    if (tid < NF) {
        PIf[tid * 4 + 0] = br1[tid]; PIf[tid * 4 + 1] = gr1[tid];
        PIf[tid * 4 + 2] = ber1[tid];
    }

    float w2c[8];
    #pragma unroll
    for (int c = 0; c < 8; ++c) w2c[c] = Wr2[c * 16 + lnm];
    const float br2v = br2[0];

    unsigned short* myF = &SH[E_MYF + wave * 2176];
    const unsigned short* WFr = &SH[0];

    const int nstrips = NEDGE / 16;          // 16380
    const int sstep   = gridDim.x * 16;      // 4096
    const int s0      = blockIdx.x * 16 + wave;

    short8 cv[4], pv[4];
    int prn[4];
    if (s0 < nstrips) {
        int pr[4];
        #pragma unroll
        for (int t = 0; t < 4; ++t) pr[t] = pidx[s0 * 16 + t * 4 + qu];
        #pragma unroll
        for (int t = 0; t < 4; ++t) {
            int e = s0 * 16 + t * 4 + qu;
            int crow = e + (int)((unsigned)e / 4095u);
            cv[t] = *(const short8*)(h2 + (size_t)crow * NF + lnm * 8);
            pv[t] = *(const short8*)(h2 + (size_t)pr[t] * NF + lnm * 8);
        }
        int s1 = s0 + sstep;
        if (s1 < nstrips) {
            #pragma unroll
            for (int t = 0; t < 4; ++t) prn[t] = pidx[s1 * 16 + t * 4 + qu];
        }
    }
    __syncthreads();

    for (int strip = s0; strip < nstrips; strip += sstep) {
        // max + convert -> A slots (edge m = t*4+qu, k = lnm*8..+7)
        #pragma unroll
        for (int t = 0; t < 4; ++t) {
            union { short8 v; unsigned short e8[8]; } u;
            #pragma unroll
            for (int j = 0; j < 8; ++j)
                u.e8[j] = f2bf(fmaxf(bf2f((unsigned short)cv[t][j]),
                                     bf2f((unsigned short)pv[t][j])));
            *(short8*)&myF[slotAddr(lnm, t * 4 + qu)] = u.v;
        }

        // prefetch next strip's rows (pidx already in prn), pidx two ahead
        int sn = strip + sstep;
        if (sn < nstrips) {
            #pragma unroll
            for (int t = 0; t < 4; ++t) {
                int e = sn * 16 + t * 4 + qu;
                int crow = e + (int)((unsigned)e / 4095u);
                cv[t] = *(const short8*)(h2 + (size_t)crow * NF + lnm * 8);
                pv[t] = *(const short8*)(h2 + (size_t)prn[t] * NF + lnm * 8);
            }
            int sn2 = sn + sstep;
            if (sn2 < nstrips) {
                #pragma unroll
                for (int t = 0; t < 4; ++t) prn[t] = pidx[sn2 * 16 + t * 4 + qu];
            }
        }

        // MFMA + LN/ELU + dot(Wr2)
        float4v acc[8];
        #pragma unroll
        for (int c = 0; c < 8; ++c) acc[c] = (float4v){0.f, 0.f, 0.f, 0.f};
        #pragma unroll
        for (int s = 0; s < 4; ++s) {
            short8 af = *(const short8*)&myF[slotAddr(s * 4 + qu, lnm)];
            #pragma unroll
            for (int c = 0; c < 8; ++c) {
                short8 bfv = *(const short8*)&WFr[((c * 4 + s) * 64 + lane) * 8];
                acc[c] = __builtin_amdgcn_mfma_f32_16x16x32_bf16(af, bfv, acc[c], 0, 0, 0);
            }
        }
        ln_elu(acc, PIf, lnm);

        #pragma unroll
        for (int r = 0; r < 4; ++r) {
            float t2 = 0.f;
            #pragma unroll
            for (int c = 0; c < 8; ++c) t2 += acc[c][r] * w2c[c];
            t2 = red16(t2);
            if (lnm == 0) rout[strip * 16 + qu * 4 + r] = t2 + br2v;
        }
    }
}

__global__ __launch_bounds__(256)
void lse_kernel(const float* __restrict__ r, float* __restrict__ out)
{
    __shared__ float red[256];
    const int b = blockIdx.x;
    const float* rb = r + (size_t)b * 4095;

    float mx = -1e30f;
    for (int i = threadIdx.x; i < 4095; i += 256) mx = fmaxf(mx, rb[i]);
    red[threadIdx.x] = mx;
    __syncthreads();
    for (int s = 128; s > 0; s >>= 1) {
        if (threadIdx.x < s) red[threadIdx.x] = fmaxf(red[threadIdx.x], red[threadIdx.x + s]);
        __syncthreads();
    }
    mx = red[0];
    __syncthreads();

    float sum = 0.f;
    for (int i = threadIdx.x; i < 4095; i += 256) sum += __expf(rb[i] - mx);
    red[threadIdx.x] = sum;
    __syncthreads();
    for (int s = 128; s > 0; s >>= 1) {
        if (threadIdx.x < s) red[threadIdx.x] += red[threadIdx.x + s];
        __syncthreads();
    }
    float lse = mx + __logf(red[0]);

    for (int i = threadIdx.x; i < 4095; i += 256)
        out[(size_t)b * 4095 + i] = rb[i] - lse;
}

extern "C" void kernel_launch(void* const* d_in, const int* in_sizes, int n_in,
                              void* d_out, int out_size, void* d_ws, size_t ws_size,
                              hipStream_t stream)
{
    const float* x    = (const float*)d_in[0];
    const int*   pidx = (const int*)d_in[1];
    const float* W1   = (const float*)d_in[2];
    const float* b1   = (const float*)d_in[3];
    const float* g1   = (const float*)d_in[4];
    const float* be1  = (const float*)d_in[5];
    const float* W2   = (const float*)d_in[6];
    const float* b2   = (const float*)d_in[7];
    const float* g2   = (const float*)d_in[8];
    const float* be2  = (const float*)d_in[9];
    const float* Wr1  = (const float*)d_in[10];
    const float* br1  = (const float*)d_in[11];
    const float* gr1  = (const float*)d_in[12];
    const float* ber1 = (const float*)d_in[13];
    const float* Wr2  = (const float*)d_in[14];
    const float* br2  = (const float*)d_in[15];
    float* out = (float*)d_out;

    // workspace: h2 (bf16, 64 MiB) | rbuf (fp32, ~1 MiB)
    unsigned short* h2 = (unsigned short*)d_ws;
    float* rbuf = (float*)(h2 + (size_t)MROWS * NF);

    fused12_kernel<<<256, 1024, 0, stream>>>(x, W1, b1, g1, be1,
                                             W2, b2, g2, be2, h2);
    edge_kernel<<<256, 1024, 0, stream>>>(h2, pidx, Wr1, br1, gr1, ber1,
                                          Wr2, br2, rbuf);
    lse_kernel<<<BATCH, 256, 0, stream>>>(rbuf, out);
}

// Round 7
// 346.723 us; speedup vs baseline: 1.0716x; 1.0222x over previous
//
#include <hip/hip_runtime.h>
#include <hip/hip_bf16.h>

#define NF     128
#define BATCH  64
#define NNODES 4096
#define MROWS  (BATCH * NNODES)       // 262144
#define NEDGE  (BATCH * (NNODES - 1)) // 262080
#define LN_EPS 1e-5f

typedef short  short8  __attribute__((ext_vector_type(8)));
typedef float  float4v __attribute__((ext_vector_type(4)));

__device__ __forceinline__ unsigned short f2bf(float f) {
    union { float f; unsigned u; } v; v.f = f;
    unsigned r = v.u;
    r = r + 0x7FFF + ((r >> 16) & 1);   // RNE
    return (unsigned short)(r >> 16);
}
__device__ __forceinline__ float bf2f(unsigned short b) {
    union { unsigned u; float f; } v; v.u = ((unsigned)b) << 16;
    return v.f;
}
// packed f32x2 -> bf16x2 (v_cvt_pk_bf16_f32), low short = lo. RNE == f2bf.
__device__ __forceinline__ unsigned pkbf(float lo, float hi) {
    __hip_bfloat162 h = __float22bfloat162_rn(float2{lo, hi});
    union { __hip_bfloat162 h; unsigned u; } v; v.h = h;
    return v.u;
}

// DPP 16-lane sum (VALU pipe, no LDS). Exact for aligned 16-lane groups.
template <int CTRL>
__device__ __forceinline__ float dppadd(float v) {
    union { float f; int i; } a, b; a.f = v;
    b.i = __builtin_amdgcn_mov_dpp(a.i, CTRL, 0xF, 0xF, true);
    return v + b.f;
}
__device__ __forceinline__ float red16(float v) {
    v = dppadd<0xB1>(v);    // quad_perm ^1
    v = dppadd<0x4E>(v);    // quad_perm ^2
    v = dppadd<0x141>(v);   // row_half_mirror (== ^4 after quad-uniform)
    v = dppadd<0x140>(v);   // row_mirror      (== ^8 after half-uniform)
    return v;
}

// A-fragment slot address (shorts): slot(q,m) holds A[m][k-octet q] (16 B).
// XOR swizzle spreads bank groups (validated r4-r6).
__device__ __forceinline__ int slotAddr(int q, int m) {
    return ((q * 16 + m) ^ (q & 7)) * 8;
}

// Stage W (128x128 fp32, k-major) into WF in bf16 MFMA B-fragment order.
// PERM: k-row k is placed at fragment position p=(k&15)*8+(k>>4), matching the
// permuted feature layout n(p)=(p&7)*16+(p>>3) used for h1-slots and h2.
template <bool PERM>
__device__ __forceinline__ void stage_wfrags(const float* __restrict__ W,
                                             unsigned short* __restrict__ WF,
                                             int tid) {
    #pragma unroll
    for (int i = 0; i < 4; ++i) {
        int g  = tid + 1024 * i;          // 0..4095
        int k  = g >> 5;                  // true input-feature row 0..127
        int n0 = (g & 31) * 4;
        float4v wv = *(const float4v*)(W + k * NF + n0);
        int p = PERM ? ((k & 15) * 8 + (k >> 4)) : k;
        int s = p >> 5, q = (p & 31) >> 3, j = p & 7;
        #pragma unroll
        for (int e = 0; e < 4; ++e) {
            int n = n0 + e;
            WF[((((n >> 4) * 4 + s) * 64) + q * 16 + (n & 15)) * 8 + j] = f2bf(wv[e]);
        }
    }
}

// bias + LayerNorm(128) + ELU on C-layout accumulators.
// PI: interleaved params PI[n*4 + {0:bias,1:gain,2:beta}] (stride-4 floats).
__device__ __forceinline__ void ln_elu(float4v acc[8], const float* __restrict__ PI,
                                       int lnm) {
    float bias[8], gn[8], bt[8];
    #pragma unroll
    for (int c = 0; c < 8; ++c) {
        float4v prm = *(const float4v*)&PI[(c * 16 + lnm) * 4];
        bias[c] = prm[0]; gn[c] = prm[1]; bt[c] = prm[2];
    }
    #pragma unroll
    for (int r = 0; r < 4; ++r) {
        float s1 = 0.f, s2 = 0.f;
        #pragma unroll
        for (int c = 0; c < 8; ++c) {
            float t = acc[c][r] + bias[c];
            acc[c][r] = t;
            s1 += t; s2 += t * t;
        }
        s1 = red16(s1);
        s2 = red16(s2);
        float mu  = s1 * (1.0f / 128.0f);
        float var = s2 * (1.0f / 128.0f) - mu * mu;
        float rs  = rsqrtf(var + LN_EPS);
        #pragma unroll
        for (int c = 0; c < 8; ++c) {
            float y = (acc[c][r] - mu) * rs * gn[c] + bt[c];
            acc[c][r] = (y > 0.f) ? y : (__expf(y) - 1.0f);
        }
    }
}

// ---------------- fused layer1+layer2 ----------------
// LDS carve (shorts): WF1 [0,16384) | WF2 [16384,32768) |
//   MYF [32768, 32768+16*2048) | PI (floats) at 65536: 2 sets x 512 floats
#define F_MYF   32768
#define F_PI    65536
#define F_TOT   (65536 + 2048)          // shorts -> 135168 B

__global__ __launch_bounds__(1024)
void fused12_kernel(const float* __restrict__ x,
                    const float* __restrict__ W1, const float* __restrict__ b1,
                    const float* __restrict__ g1, const float* __restrict__ be1,
                    const float* __restrict__ W2, const float* __restrict__ b2,
                    const float* __restrict__ g2, const float* __restrict__ be2,
                    unsigned short* __restrict__ h2out)
{
    __shared__ __align__(16) unsigned short SH[F_TOT];

    const int tid  = threadIdx.x;
    const int lane = tid & 63;
    const int wave = tid >> 6;        // 0..15
    const int lnm  = lane & 15;
    const int qu   = lane >> 4;

    stage_wfrags<false>(W1, &SH[0], tid);
    stage_wfrags<true >(W2, &SH[16384], tid);
    float* PIf = (float*)&SH[F_PI];
    if (tid < NF) {
        PIf[tid * 4 + 0] = b1[tid]; PIf[tid * 4 + 1] = g1[tid]; PIf[tid * 4 + 2] = be1[tid];
        PIf[512 + tid * 4 + 0] = b2[tid]; PIf[512 + tid * 4 + 1] = g2[tid];
        PIf[512 + tid * 4 + 2] = be2[tid];
    }

    unsigned short* myF = &SH[F_MYF + wave * 2048];
    const unsigned short* WF1 = &SH[0];
    const unsigned short* WF2 = &SH[16384];

    const int nstrips = MROWS / 16;          // 16384
    const int sstep   = gridDim.x * 16;      // 4096
    int strip = blockIdx.x * 16 + wave;

    float4v rx[8];
    if (strip < nstrips) {
        const float* xs = x + (size_t)strip * (16 * NF);
        #pragma unroll
        for (int t = 0; t < 8; ++t)
            rx[t] = *(const float4v*)(xs + t * 256 + lane * 4);
    }
    __syncthreads();

    const int qx = (lane & 31) >> 1;   // k-octet of this lane's x chunk
    const int hx = (lane & 1) * 4;     // half-slot offset (shorts)

    for (; strip < nstrips; strip += sstep) {
        const size_t rowBase = (size_t)strip * 16;

        // stage x (true feature order): rows t*2+(lane>>5), cols (lane&31)*4..+3
        #pragma unroll
        for (int t = 0; t < 8; ++t) {
            int m = t * 2 + (lane >> 5);
            uint2 u = { pkbf(rx[t][0], rx[t][1]), pkbf(rx[t][2], rx[t][3]) };
            *(uint2*)&myF[slotAddr(qx, m) + hx] = u;
        }
        // prefetch strip i+1 (in flight through all compute below)
        int sn = strip + sstep;
        if (sn < nstrips) {
            const float* xs = x + (size_t)sn * (16 * NF);
            #pragma unroll
            for (int t = 0; t < 8; ++t)
                rx[t] = *(const float4v*)(xs + t * 256 + lane * 4);
        }

        // layer 1 MFMA
        float4v acc[8];
        #pragma unroll
        for (int c = 0; c < 8; ++c) acc[c] = (float4v){0.f, 0.f, 0.f, 0.f};
        #pragma unroll
        for (int s = 0; s < 4; ++s) {
            short8 af = *(const short8*)&myF[slotAddr(s * 4 + qu, lnm)];
            #pragma unroll
            for (int c = 0; c < 8; ++c) {
                short8 bfv = *(const short8*)&WF1[((c * 4 + s) * 64 + lane) * 8];
                acc[c] = __builtin_amdgcn_mfma_f32_16x16x32_bf16(af, bfv, acc[c], 0, 0, 0);
            }
        }
        ln_elu(acc, PIf, lnm);

        // L2 repack in PERMUTED feature order: lane's 8 c-values for row
        // m=qu*4+r are contiguous at positions lnm*8..+7 -> one b128 per r.
        // (LDS ops are in-order per wave: these writes can't pass the reads.)
        #pragma unroll
        for (int r = 0; r < 4; ++r) {
            uint4 u;
            u.x = pkbf(acc[0][r], acc[1][r]);
            u.y = pkbf(acc[2][r], acc[3][r]);
            u.z = pkbf(acc[4][r], acc[5][r]);
            u.w = pkbf(acc[6][r], acc[7][r]);
            *(uint4*)&myF[slotAddr(lnm, qu * 4 + r)] = u;
        }

        // layer 2 MFMA (WF2 staged with matching k-permutation)
        #pragma unroll
        for (int c = 0; c < 8; ++c) acc[c] = (float4v){0.f, 0.f, 0.f, 0.f};
        #pragma unroll
        for (int s = 0; s < 4; ++s) {
            short8 af = *(const short8*)&myF[slotAddr(s * 4 + qu, lnm)];
            #pragma unroll
            for (int c = 0; c < 8; ++c) {
                short8 bfv = *(const short8*)&WF2[((c * 4 + s) * 64 + lane) * 8];
                acc[c] = __builtin_amdgcn_mfma_f32_16x16x32_bf16(af, bfv, acc[c], 0, 0, 0);
            }
        }
        ln_elu(acc, PIf + 512, lnm);

        // store h2 DIRECTLY from registers in permuted feature layout:
        // position p=lnm*8+c of row holds feature 16c+lnm. 16 B/lane, rows
        // qu*4+r: 4 fully-covered 256-B segments per instruction.
        #pragma unroll
        for (int r = 0; r < 4; ++r) {
            uint4 u;
            u.x = pkbf(acc[0][r], acc[1][r]);
            u.y = pkbf(acc[2][r], acc[3][r]);
            u.z = pkbf(acc[4][r], acc[5][r]);
            u.w = pkbf(acc[6][r], acc[7][r]);
            *(uint4*)(h2out + (rowBase + qu * 4 + r) * NF + lnm * 8) = u;
        }
    }
}

// ---------------- edge kernel ----------------
// h2 is in permuted feature layout; Wr1 staged with the same k-permutation.
// LDS carve: WFr [0,16384) | MYF [16384,16384+16*2048) | PI at 49152 shorts
#define E_MYF   16384
#define E_PI    49152
#define E_TOT   (49152 + 1024)          // shorts -> 100352 B

__global__ __launch_bounds__(1024)
void edge_kernel(const unsigned short* __restrict__ h2,
                 const int* __restrict__ pidx,
                 const float* __restrict__ Wr1, const float* __restrict__ br1,
                 const float* __restrict__ gr1, const float* __restrict__ ber1,
                 const float* __restrict__ Wr2, const float* __restrict__ br2,
                 float* __restrict__ rout)
{
    __shared__ __align__(16) unsigned short SH[E_TOT];

    const int tid  = threadIdx.x;
    const int lane = tid & 63;
    const int wave = tid >> 6;
    const int lnm  = lane & 15;
    const int qu   = lane >> 4;

    stage_wfrags<true>(Wr1, &SH[0], tid);
    float* PIf = (float*)&SH[E_PI];
    if (tid < NF) {
        PIf[tid * 4 + 0] = br1[tid]; PIf[tid * 4 + 1] = gr1[tid];
        PIf[tid * 4 + 2] = ber1[tid];
    }

    float w2c[8];
    #pragma unroll
    for (int c = 0; c < 8; ++c) w2c[c] = Wr2[c * 16 + lnm];
    const float br2v = br2[0];

    unsigned short* myF = &SH[E_MYF + wave * 2048];
    const unsigned short* WFr = &SH[0];

    const int nstrips = NEDGE / 16;          // 16380
    const int sstep   = gridDim.x * 16;      // 4096
    const int s0      = blockIdx.x * 16 + wave;

    short8 cv[4], pv[4];
    int prn[4];
    if (s0 < nstrips) {
        int pr[4];
        #pragma unroll
        for (int t = 0; t < 4; ++t) pr[t] = pidx[s0 * 16 + t * 4 + qu];
        #pragma unroll
        for (int t = 0; t < 4; ++t) {
            int e = s0 * 16 + t * 4 + qu;
            int crow = e + (int)((unsigned)e / 4095u);
            cv[t] = *(const short8*)(h2 + (size_t)crow * NF + lnm * 8);
            pv[t] = *(const short8*)(h2 + (size_t)pr[t] * NF + lnm * 8);
        }
        int s1 = s0 + sstep;
        if (s1 < nstrips) {
            #pragma unroll
            for (int t = 0; t < 4; ++t) prn[t] = pidx[s1 * 16 + t * 4 + qu];
        }
    }
    __syncthreads();

    for (int strip = s0; strip < nstrips; strip += sstep) {
        // max in fp32, pack pairs, one b128 slot write per t
        #pragma unroll
        for (int t = 0; t < 4; ++t) {
            float m0 = fmaxf(bf2f((unsigned short)cv[t][0]), bf2f((unsigned short)pv[t][0]));
            float m1 = fmaxf(bf2f((unsigned short)cv[t][1]), bf2f((unsigned short)pv[t][1]));
            float m2 = fmaxf(bf2f((unsigned short)cv[t][2]), bf2f((unsigned short)pv[t][2]));
            float m3 = fmaxf(bf2f((unsigned short)cv[t][3]), bf2f((unsigned short)pv[t][3]));
            float m4 = fmaxf(bf2f((unsigned short)cv[t][4]), bf2f((unsigned short)pv[t][4]));
            float m5 = fmaxf(bf2f((unsigned short)cv[t][5]), bf2f((unsigned short)pv[t][5]));
            float m6 = fmaxf(bf2f((unsigned short)cv[t][6]), bf2f((unsigned short)pv[t][6]));
            float m7 = fmaxf(bf2f((unsigned short)cv[t][7]), bf2f((unsigned short)pv[t][7]));
            uint4 u;
            u.x = pkbf(m0, m1); u.y = pkbf(m2, m3);
            u.z = pkbf(m4, m5); u.w = pkbf(m6, m7);
            *(uint4*)&myF[slotAddr(lnm, t * 4 + qu)] = u;
        }

        // prefetch next strip's rows (pidx already in prn), pidx two ahead
        int sn = strip + sstep;
        if (sn < nstrips) {
            #pragma unroll
            for (int t = 0; t < 4; ++t) {
                int e = sn * 16 + t * 4 + qu;
                int crow = e + (int)((unsigned)e / 4095u);
                cv[t] = *(const short8*)(h2 + (size_t)crow * NF + lnm * 8);
                pv[t] = *(const short8*)(h2 + (size_t)prn[t] * NF + lnm * 8);
            }
            int sn2 = sn + sstep;
            if (sn2 < nstrips) {
                #pragma unroll
                for (int t = 0; t < 4; ++t) prn[t] = pidx[sn2 * 16 + t * 4 + qu];
            }
        }

        // MFMA + LN/ELU + dot(Wr2)
        float4v acc[8];
        #pragma unroll
        for (int c = 0; c < 8; ++c) acc[c] = (float4v){0.f, 0.f, 0.f, 0.f};
        #pragma unroll
        for (int s = 0; s < 4; ++s) {
            short8 af = *(const short8*)&myF[slotAddr(s * 4 + qu, lnm)];
            #pragma unroll
            for (int c = 0; c < 8; ++c) {
                short8 bfv = *(const short8*)&WFr[((c * 4 + s) * 64 + lane) * 8];
                acc[c] = __builtin_amdgcn_mfma_f32_16x16x32_bf16(af, bfv, acc[c], 0, 0, 0);
            }
        }
        ln_elu(acc, PIf, lnm);

        #pragma unroll
        for (int r = 0; r < 4; ++r) {
            float t2 = 0.f;
            #pragma unroll
            for (int c = 0; c < 8; ++c) t2 += acc[c][r] * w2c[c];
            t2 = red16(t2);
            if (lnm == 0) rout[strip * 16 + qu * 4 + r] = t2 + br2v;
        }
    }
}

__global__ __launch_bounds__(1024)
void lse_kernel(const float* __restrict__ r, float* __restrict__ out)
{
    __shared__ float red[1024];
    const int b = blockIdx.x;
    const float* rb = r + (size_t)b * 4095;

    float mx = -1e30f;
    for (int i = threadIdx.x; i < 4095; i += 1024) mx = fmaxf(mx, rb[i]);
    red[threadIdx.x] = mx;
    __syncthreads();
    for (int s = 512; s > 0; s >>= 1) {
        if (threadIdx.x < s) red[threadIdx.x] = fmaxf(red[threadIdx.x], red[threadIdx.x + s]);
        __syncthreads();
    }
    mx = red[0];
    __syncthreads();

    float sum = 0.f;
    for (int i = threadIdx.x; i < 4095; i += 1024) sum += __expf(rb[i] - mx);
    red[threadIdx.x] = sum;
    __syncthreads();
    for (int s = 512; s > 0; s >>= 1) {
        if (threadIdx.x < s) red[threadIdx.x] += red[threadIdx.x + s];
        __syncthreads();
    }
    float lse = mx + __logf(red[0]);

    for (int i = threadIdx.x; i < 4095; i += 1024)
        out[(size_t)b * 4095 + i] = rb[i] - lse;
}

extern "C" void kernel_launch(void* const* d_in, const int* in_sizes, int n_in,
                              void* d_out, int out_size, void* d_ws, size_t ws_size,
                              hipStream_t stream)
{
    const float* x    = (const float*)d_in[0];
    const int*   pidx = (const int*)d_in[1];
    const float* W1   = (const float*)d_in[2];
    const float* b1   = (const float*)d_in[3];
    const float* g1   = (const float*)d_in[4];
    const float* be1  = (const float*)d_in[5];
    const float* W2   = (const float*)d_in[6];
    const float* b2   = (const float*)d_in[7];
    const float* g2   = (const float*)d_in[8];
    const float* be2  = (const float*)d_in[9];
    const float* Wr1  = (const float*)d_in[10];
    const float* br1  = (const float*)d_in[11];
    const float* gr1  = (const float*)d_in[12];
    const float* ber1 = (const float*)d_in[13];
    const float* Wr2  = (const float*)d_in[14];
    const float* br2  = (const float*)d_in[15];
    float* out = (float*)d_out;

    // workspace: h2 (bf16, 64 MiB, permuted feature layout) | rbuf (fp32)
    unsigned short* h2 = (unsigned short*)d_ws;
    float* rbuf = (float*)(h2 + (size_t)MROWS * NF);

    fused12_kernel<<<256, 1024, 0, stream>>>(x, W1, b1, g1, be1,
                                             W2, b2, g2, be2, h2);
    edge_kernel<<<256, 1024, 0, stream>>>(h2, pidx, Wr1, br1, gr1, ber1,
                                          Wr2, br2, rbuf);
    lse_kernel<<<BATCH, 1024, 0, stream>>>(rbuf, out);
}

// Round 8
// 344.293 us; speedup vs baseline: 1.0792x; 1.0071x over previous
//
#include <hip/hip_runtime.h>
#include <hip/hip_bf16.h>

#define NF     128
#define BATCH  64
#define NNODES 4096
#define MROWS  (BATCH * NNODES)       // 262144
#define NEDGE  (BATCH * (NNODES - 1)) // 262080
#define LN_EPS 1e-5f

typedef short  short8  __attribute__((ext_vector_type(8)));
typedef float  float4v __attribute__((ext_vector_type(4)));

__device__ __forceinline__ unsigned short f2bf(float f) {
    union { float f; unsigned u; } v; v.f = f;
    unsigned r = v.u;
    r = r + 0x7FFF + ((r >> 16) & 1);   // RNE
    return (unsigned short)(r >> 16);
}
__device__ __forceinline__ float bf2f(unsigned short b) {
    union { unsigned u; float f; } v; v.u = ((unsigned)b) << 16;
    return v.f;
}
// packed f32x2 -> bf16x2 (v_cvt_pk_bf16_f32), low short = lo. RNE == f2bf.
__device__ __forceinline__ unsigned pkbf(float lo, float hi) {
    __hip_bfloat162 h = __float22bfloat162_rn(float2{lo, hi});
    union { __hip_bfloat162 h; unsigned u; } v; v.h = h;
    return v.u;
}

// DPP 16-lane sum (VALU pipe, no LDS). Exact for aligned 16-lane groups.
template <int CTRL>
__device__ __forceinline__ float dppadd(float v) {
    union { float f; int i; } a, b; a.f = v;
    b.i = __builtin_amdgcn_mov_dpp(a.i, CTRL, 0xF, 0xF, true);
    return v + b.f;
}
__device__ __forceinline__ float red16(float v) {
    v = dppadd<0xB1>(v);    // quad_perm ^1
    v = dppadd<0x4E>(v);    // quad_perm ^2
    v = dppadd<0x141>(v);   // row_half_mirror (== ^4 after quad-uniform)
    v = dppadd<0x140>(v);   // row_mirror      (== ^8 after half-uniform)
    return v;
}

// A-fragment slot address (shorts): slot(q,m) holds A[m][k-octet q] (16 B).
// XOR swizzle spreads bank groups (validated r4-r6).
__device__ __forceinline__ int slotAddr(int q, int m) {
    return ((q * 16 + m) ^ (q & 7)) * 8;
}

// Stage W (128x128 fp32, k-major) into WF in bf16 MFMA B-fragment order.
// PERM: k-row k is placed at fragment position p=(k&15)*8+(k>>4), matching the
// permuted feature layout n(p)=(p&7)*16+(p>>3) used for h1-slots and h2.
template <bool PERM>
__device__ __forceinline__ void stage_wfrags(const float* __restrict__ W,
                                             unsigned short* __restrict__ WF,
                                             int tid) {
    #pragma unroll
    for (int i = 0; i < 4; ++i) {
        int g  = tid + 1024 * i;          // 0..4095
        int k  = g >> 5;                  // true input-feature row 0..127
        int n0 = (g & 31) * 4;
        float4v wv = *(const float4v*)(W + k * NF + n0);
        int p = PERM ? ((k & 15) * 8 + (k >> 4)) : k;
        int s = p >> 5, q = (p & 31) >> 3, j = p & 7;
        #pragma unroll
        for (int e = 0; e < 4; ++e) {
            int n = n0 + e;
            WF[((((n >> 4) * 4 + s) * 64) + q * 16 + (n & 15)) * 8 + j] = f2bf(wv[e]);
        }
    }
}

// bias + LayerNorm(128) + ELU on C-layout accumulators.
// PI: interleaved params PI[n*4 + {0:bias,1:gain,2:beta}] (stride-4 floats).
__device__ __forceinline__ void ln_elu(float4v acc[8], const float* __restrict__ PI,
                                       int lnm) {
    float bias[8], gn[8], bt[8];
    #pragma unroll
    for (int c = 0; c < 8; ++c) {
        float4v prm = *(const float4v*)&PI[(c * 16 + lnm) * 4];
        bias[c] = prm[0]; gn[c] = prm[1]; bt[c] = prm[2];
    }
    #pragma unroll
    for (int r = 0; r < 4; ++r) {
        float s1 = 0.f, s2 = 0.f;
        #pragma unroll
        for (int c = 0; c < 8; ++c) {
            float t = acc[c][r] + bias[c];
            acc[c][r] = t;
            s1 += t; s2 += t * t;
        }
        s1 = red16(s1);
        s2 = red16(s2);
        float mu  = s1 * (1.0f / 128.0f);
        float var = s2 * (1.0f / 128.0f) - mu * mu;
        float rs  = rsqrtf(var + LN_EPS);
        #pragma unroll
        for (int c = 0; c < 8; ++c) {
            float y = (acc[c][r] - mu) * rs * gn[c] + bt[c];
            acc[c][r] = (y > 0.f) ? y : (__expf(y) - 1.0f);
        }
    }
}

// ---------------- fused layer1+layer2 ----------------
// LDS carve (shorts): WF1 [0,16384) | WF2 [16384,32768) |
//   MYF [32768, 32768+16*2048) | PI (floats) at 65536: 2 sets x 512 floats
#define F_MYF   32768
#define F_PI    65536
#define F_TOT   (65536 + 2048)          // shorts -> 135168 B

// LDS pins us to 1 block/CU (135 KB): declare 4 waves/EU so the register
// allocator gets the full 128-VGPR budget instead of squeezing to 64 for an
// occupancy level LDS makes impossible.
__global__ __launch_bounds__(1024, 4)
void fused12_kernel(const float* __restrict__ x,
                    const float* __restrict__ W1, const float* __restrict__ b1,
                    const float* __restrict__ g1, const float* __restrict__ be1,
                    const float* __restrict__ W2, const float* __restrict__ b2,
                    const float* __restrict__ g2, const float* __restrict__ be2,
                    unsigned short* __restrict__ h2out)
{
    __shared__ __align__(16) unsigned short SH[F_TOT];

    const int tid  = threadIdx.x;
    const int lane = tid & 63;
    const int wave = tid >> 6;        // 0..15
    const int lnm  = lane & 15;
    const int qu   = lane >> 4;

    stage_wfrags<false>(W1, &SH[0], tid);
    stage_wfrags<true >(W2, &SH[16384], tid);
    float* PIf = (float*)&SH[F_PI];
    if (tid < NF) {
        PIf[tid * 4 + 0] = b1[tid]; PIf[tid * 4 + 1] = g1[tid]; PIf[tid * 4 + 2] = be1[tid];
        PIf[512 + tid * 4 + 0] = b2[tid]; PIf[512 + tid * 4 + 1] = g2[tid];
        PIf[512 + tid * 4 + 2] = be2[tid];
    }

    unsigned short* myF = &SH[F_MYF + wave * 2048];
    const unsigned short* WF1 = &SH[0];
    const unsigned short* WF2 = &SH[16384];

    const int nstrips = MROWS / 16;          // 16384
    const int sstep   = gridDim.x * 16;      // 4096
    int strip = blockIdx.x * 16 + wave;

    float4v rx[8];
    if (strip < nstrips) {
        const float* xs = x + (size_t)strip * (16 * NF);
        #pragma unroll
        for (int t = 0; t < 8; ++t)
            rx[t] = *(const float4v*)(xs + t * 256 + lane * 4);
    }
    __syncthreads();

    const int qx = (lane & 31) >> 1;   // k-octet of this lane's x chunk
    const int hx = (lane & 1) * 4;     // half-slot offset (shorts)

    for (; strip < nstrips; strip += sstep) {
        const size_t rowBase = (size_t)strip * 16;

        // stage x (true feature order): rows t*2+(lane>>5), cols (lane&31)*4..+3
        #pragma unroll
        for (int t = 0; t < 8; ++t) {
            int m = t * 2 + (lane >> 5);
            uint2 u = { pkbf(rx[t][0], rx[t][1]), pkbf(rx[t][2], rx[t][3]) };
            *(uint2*)&myF[slotAddr(qx, m) + hx] = u;
        }
        // prefetch strip i+1 (in flight through all compute below)
        int sn = strip + sstep;
        if (sn < nstrips) {
            const float* xs = x + (size_t)sn * (16 * NF);
            #pragma unroll
            for (int t = 0; t < 8; ++t)
                rx[t] = *(const float4v*)(xs + t * 256 + lane * 4);
        }

        // layer 1 MFMA
        float4v acc[8];
        #pragma unroll
        for (int c = 0; c < 8; ++c) acc[c] = (float4v){0.f, 0.f, 0.f, 0.f};
        #pragma unroll
        for (int s = 0; s < 4; ++s) {
            short8 af = *(const short8*)&myF[slotAddr(s * 4 + qu, lnm)];
            #pragma unroll
            for (int c = 0; c < 8; ++c) {
                short8 bfv = *(const short8*)&WF1[((c * 4 + s) * 64 + lane) * 8];
                acc[c] = __builtin_amdgcn_mfma_f32_16x16x32_bf16(af, bfv, acc[c], 0, 0, 0);
            }
        }
        ln_elu(acc, PIf, lnm);

        // L2 repack in PERMUTED feature order: lane's 8 c-values for row
        // m=qu*4+r are contiguous at positions lnm*8..+7 -> one b128 per r.
        // (LDS ops are in-order per wave: these writes can't pass the reads.)
        #pragma unroll
        for (int r = 0; r < 4; ++r) {
            uint4 u;
            u.x = pkbf(acc[0][r], acc[1][r]);
            u.y = pkbf(acc[2][r], acc[3][r]);
            u.z = pkbf(acc[4][r], acc[5][r]);
            u.w = pkbf(acc[6][r], acc[7][r]);
            *(uint4*)&myF[slotAddr(lnm, qu * 4 + r)] = u;
        }

        // layer 2 MFMA (WF2 staged with matching k-permutation)
        #pragma unroll
        for (int c = 0; c < 8; ++c) acc[c] = (float4v){0.f, 0.f, 0.f, 0.f};
        #pragma unroll
        for (int s = 0; s < 4; ++s) {
            short8 af = *(const short8*)&myF[slotAddr(s * 4 + qu, lnm)];
            #pragma unroll
            for (int c = 0; c < 8; ++c) {
                short8 bfv = *(const short8*)&WF2[((c * 4 + s) * 64 + lane) * 8];
                acc[c] = __builtin_amdgcn_mfma_f32_16x16x32_bf16(af, bfv, acc[c], 0, 0, 0);
            }
        }
        ln_elu(acc, PIf + 512, lnm);

        // store h2 DIRECTLY from registers in permuted feature layout:
        // position p=lnm*8+c of row holds feature 16c+lnm. 16 B/lane, rows
        // qu*4+r: 4 fully-covered 256-B segments per instruction.
        #pragma unroll
        for (int r = 0; r < 4; ++r) {
            uint4 u;
            u.x = pkbf(acc[0][r], acc[1][r]);
            u.y = pkbf(acc[2][r], acc[3][r]);
            u.z = pkbf(acc[4][r], acc[5][r]);
            u.w = pkbf(acc[6][r], acc[7][r]);
            *(uint4*)(h2out + (rowBase + qu * 4 + r) * NF + lnm * 8) = u;
        }
    }
}

// ---------------- edge kernel ----------------
// h2 is in permuted feature layout; Wr1 staged with the same k-permutation.
// LDS carve: WFr [0,16384) | MYF [16384,16384+16*2048) | PI at 49152 shorts
#define E_MYF   16384
#define E_PI    49152
#define E_TOT   (49152 + 1024)          // shorts -> 100352 B

__global__ __launch_bounds__(1024, 4)
void edge_kernel(const unsigned short* __restrict__ h2,
                 const int* __restrict__ pidx,
                 const float* __restrict__ Wr1, const float* __restrict__ br1,
                 const float* __restrict__ gr1, const float* __restrict__ ber1,
                 const float* __restrict__ Wr2, const float* __restrict__ br2,
                 float* __restrict__ rout)
{
    __shared__ __align__(16) unsigned short SH[E_TOT];

    const int tid  = threadIdx.x;
    const int lane = tid & 63;
    const int wave = tid >> 6;
    const int lnm  = lane & 15;
    const int qu   = lane >> 4;

    stage_wfrags<true>(Wr1, &SH[0], tid);
    float* PIf = (float*)&SH[E_PI];
    if (tid < NF) {
        PIf[tid * 4 + 0] = br1[tid]; PIf[tid * 4 + 1] = gr1[tid];
        PIf[tid * 4 + 2] = ber1[tid];
    }

    float w2c[8];
    #pragma unroll
    for (int c = 0; c < 8; ++c) w2c[c] = Wr2[c * 16 + lnm];
    const float br2v = br2[0];

    unsigned short* myF = &SH[E_MYF + wave * 2048];
    const unsigned short* WFr = &SH[0];

    const int nstrips = NEDGE / 16;          // 16380
    const int sstep   = gridDim.x * 16;      // 4096
    const int s0      = blockIdx.x * 16 + wave;

    short8 cv[4], pv[4];
    int prn[4];
    if (s0 < nstrips) {
        int pr[4];
        #pragma unroll
        for (int t = 0; t < 4; ++t) pr[t] = pidx[s0 * 16 + t * 4 + qu];
        #pragma unroll
        for (int t = 0; t < 4; ++t) {
            int e = s0 * 16 + t * 4 + qu;
            int crow = e + (int)((unsigned)e / 4095u);
            cv[t] = *(const short8*)(h2 + (size_t)crow * NF + lnm * 8);
            pv[t] = *(const short8*)(h2 + (size_t)pr[t] * NF + lnm * 8);
        }
        int s1 = s0 + sstep;
        if (s1 < nstrips) {
            #pragma unroll
            for (int t = 0; t < 4; ++t) prn[t] = pidx[s1 * 16 + t * 4 + qu];
        }
    }
    __syncthreads();

    for (int strip = s0; strip < nstrips; strip += sstep) {
        // max in fp32, pack pairs, one b128 slot write per t
        #pragma unroll
        for (int t = 0; t < 4; ++t) {
            float m0 = fmaxf(bf2f((unsigned short)cv[t][0]), bf2f((unsigned short)pv[t][0]));
            float m1 = fmaxf(bf2f((unsigned short)cv[t][1]), bf2f((unsigned short)pv[t][1]));
            float m2 = fmaxf(bf2f((unsigned short)cv[t][2]), bf2f((unsigned short)pv[t][2]));
            float m3 = fmaxf(bf2f((unsigned short)cv[t][3]), bf2f((unsigned short)pv[t][3]));
            float m4 = fmaxf(bf2f((unsigned short)cv[t][4]), bf2f((unsigned short)pv[t][4]));
            float m5 = fmaxf(bf2f((unsigned short)cv[t][5]), bf2f((unsigned short)pv[t][5]));
            float m6 = fmaxf(bf2f((unsigned short)cv[t][6]), bf2f((unsigned short)pv[t][6]));
            float m7 = fmaxf(bf2f((unsigned short)cv[t][7]), bf2f((unsigned short)pv[t][7]));
            uint4 u;
            u.x = pkbf(m0, m1); u.y = pkbf(m2, m3);
            u.z = pkbf(m4, m5); u.w = pkbf(m6, m7);
            *(uint4*)&myF[slotAddr(lnm, t * 4 + qu)] = u;
        }

        // prefetch next strip's rows (pidx already in prn), pidx two ahead
        int sn = strip + sstep;
        if (sn < nstrips) {
            #pragma unroll
            for (int t = 0; t < 4; ++t) {
                int e = sn * 16 + t * 4 + qu;
                int crow = e + (int)((unsigned)e / 4095u);
                cv[t] = *(const short8*)(h2 + (size_t)crow * NF + lnm * 8);
                pv[t] = *(const short8*)(h2 + (size_t)prn[t] * NF + lnm * 8);
            }
            int sn2 = sn + sstep;
            if (sn2 < nstrips) {
                #pragma unroll
                for (int t = 0; t < 4; ++t) prn[t] = pidx[sn2 * 16 + t * 4 + qu];
            }
        }

        // MFMA + LN/ELU + dot(Wr2)
        float4v acc[8];
        #pragma unroll
        for (int c = 0; c < 8; ++c) acc[c] = (float4v){0.f, 0.f, 0.f, 0.f};
        #pragma unroll
        for (int s = 0; s < 4; ++s) {
            short8 af = *(const short8*)&myF[slotAddr(s * 4 + qu, lnm)];
            #pragma unroll
            for (int c = 0; c < 8; ++c) {
                short8 bfv = *(const short8*)&WFr[((c * 4 + s) * 64 + lane) * 8];
                acc[c] = __builtin_amdgcn_mfma_f32_16x16x32_bf16(af, bfv, acc[c], 0, 0, 0);
            }
        }
        ln_elu(acc, PIf, lnm);

        #pragma unroll
        for (int r = 0; r < 4; ++r) {
            float t2 = 0.f;
            #pragma unroll
            for (int c = 0; c < 8; ++c) t2 += acc[c][r] * w2c[c];
            t2 = red16(t2);
            if (lnm == 0) rout[strip * 16 + qu * 4 + r] = t2 + br2v;
        }
    }
}

__global__ __launch_bounds__(1024)
void lse_kernel(const float* __restrict__ r, float* __restrict__ out)
{
    __shared__ float red[1024];
    const int b = blockIdx.x;
    const float* rb = r + (size_t)b * 4095;

    float mx = -1e30f;
    for (int i = threadIdx.x; i < 4095; i += 1024) mx = fmaxf(mx, rb[i]);
    red[threadIdx.x] = mx;
    __syncthreads();
    for (int s = 512; s > 0; s >>= 1) {
        if (threadIdx.x < s) red[threadIdx.x] = fmaxf(red[threadIdx.x], red[threadIdx.x + s]);
        __syncthreads();
    }
    mx = red[0];
    __syncthreads();

    float sum = 0.f;
    for (int i = threadIdx.x; i < 4095; i += 1024) sum += __expf(rb[i] - mx);
    red[threadIdx.x] = sum;
    __syncthreads();
    for (int s = 512; s > 0; s >>= 1) {
        if (threadIdx.x < s) red[threadIdx.x] += red[threadIdx.x + s];
        __syncthreads();
    }
    float lse = mx + __logf(red[0]);

    for (int i = threadIdx.x; i < 4095; i += 1024)
        out[(size_t)b * 4095 + i] = rb[i] - lse;
}

extern "C" void kernel_launch(void* const* d_in, const int* in_sizes, int n_in,
                              void* d_out, int out_size, void* d_ws, size_t ws_size,
                              hipStream_t stream)
{
    const float* x    = (const float*)d_in[0];
    const int*   pidx = (const int*)d_in[1];
    const float* W1   = (const float*)d_in[2];
    const float* b1   = (const float*)d_in[3];
    const float* g1   = (const float*)d_in[4];
    const float* be1  = (const float*)d_in[5];
    const float* W2   = (const float*)d_in[6];
    const float* b2   = (const float*)d_in[7];
    const float* g2   = (const float*)d_in[8];
    const float* be2  = (const float*)d_in[9];
    const float* Wr1  = (const float*)d_in[10];
    const float* br1  = (const float*)d_in[11];
    const float* gr1  = (const float*)d_in[12];
    const float* ber1 = (const float*)d_in[13];
    const float* Wr2  = (const float*)d_in[14];
    const float* br2  = (const float*)d_in[15];
    float* out = (float*)d_out;

    // workspace: h2 (bf16, 64 MiB, permuted feature layout) | rbuf (fp32)
    unsigned short* h2 = (unsigned short*)d_ws;
    float* rbuf = (float*)(h2 + (size_t)MROWS * NF);

    fused12_kernel<<<256, 1024, 0, stream>>>(x, W1, b1, g1, be1,
                                             W2, b2, g2, be2, h2);
    edge_kernel<<<256, 1024, 0, stream>>>(h2, pidx, Wr1, br1, gr1, ber1,
                                          Wr2, br2, rbuf);
    lse_kernel<<<BATCH, 1024, 0, stream>>>(rbuf, out);
}